// Round 10
// baseline (294.949 us; speedup 1.0000x reference)
//
#include <hip/hip_runtime.h>
#include <hip/hip_bf16.h>

#define B_ 4
#define N_ 2048
#define F_ 256
#define H_ 8
#define O_ 256

// log2(e)/16 folded into Q so softmax can use exp2f (exact softmax, monotone map)
#define SCALE_QK 0.09016844005556021f

typedef __attribute__((ext_vector_type(8))) short short8;
typedef __attribute__((ext_vector_type(4))) short s16x4;
typedef __attribute__((ext_vector_type(4))) float f32x4;
typedef __attribute__((ext_vector_type(4))) unsigned int u32x4;

static __device__ __forceinline__ float bf2f(short u) {
    unsigned int x = ((unsigned int)(unsigned short)u) << 16;
    return __builtin_bit_cast(float, x);
}
static __device__ __forceinline__ short f2bf(float f) {
    unsigned int x = __builtin_bit_cast(unsigned int, f);
    unsigned int lsb = (x >> 16) & 1u;
    x += 0x7fffu + lsb;
    return (short)(x >> 16);
}
// packed f32x2 -> bf16x2 in one instruction (RNE); no builtin on gfx950
static __device__ __forceinline__ unsigned int cvtpk(float a, float b) {
    unsigned int r;
    asm("v_cvt_pk_bf16_f32 %0, %1, %2" : "=v"(r) : "v"(a), "v"(b));
    return r;
}

// async global->LDS 16B/lane; LDS dst is wave-uniform base + lane*16
static __device__ __forceinline__ void gld16(const short* g, short* l) {
    __builtin_amdgcn_global_load_lds(
        (const __attribute__((address_space(1))) void*)g,
        (__attribute__((address_space(3))) void*)l, 16, 0, 0);
}

// ====== merged prep: f32 -> bf16 transpose (+ optional straight copy) ======
// One launch covers all three conversions (they were independent but
// stream-serialized as 3 launches). Body = the session-verified cvtT tile.
//   id 0..511     : Wh   (8 batches, 256x256)  -> WhT
//   id 512..1023  : Wout (2048x256)            -> WoutT
//   id 1024..3071 : nodes (4 batches, 2048x256)-> XT, + straight copy -> Xbf
__global__ __launch_bounds__(256) void prep_kernel(const float* __restrict__ nodes,
                                                   const float* __restrict__ Wh,
                                                   const float* __restrict__ Wout,
                                                   short* __restrict__ Xbf,
                                                   short* __restrict__ XT,
                                                   short* __restrict__ WhT,
                                                   short* __restrict__ WoutT) {
    __shared__ short tile[32][33];
    int id = blockIdx.x;
    const float* src; short* dstT; short* dst2; int R, C, bx, by;
    if (id < 512) {            // Wh batch z, grid-equiv (8,8)
        int z = id >> 6, rem = id & 63;
        src = Wh + (size_t)z * 65536; dstT = WhT + (size_t)z * 65536; dst2 = nullptr;
        R = 256; C = 256; bx = rem & 7; by = rem >> 3;
    } else if (id < 1024) {    // Wout, grid-equiv (8,64)
        int rem = id - 512;
        src = Wout; dstT = WoutT; dst2 = nullptr;
        R = 2048; C = 256; bx = rem & 7; by = rem >> 3;
    } else {                   // nodes batch z, grid-equiv (8,64)
        int rem = id - 1024;
        int z = rem >> 9; rem &= 511;
        src = nodes + (size_t)z * 524288; dstT = XT + (size_t)z * 524288;
        dst2 = Xbf + (size_t)z * 524288;
        R = 2048; C = 256; bx = rem & 7; by = rem >> 3;
    }
    int tx = threadIdx.x, ty = threadIdx.y;           // 32 x 8
    int c0 = bx * 32, r0 = by * 32;
#pragma unroll
    for (int j = 0; j < 4; j++) {
        int r = r0 + ty + j * 8;
        short v = f2bf(src[(size_t)r * C + c0 + tx]);
        tile[ty + j * 8][tx] = v;
        if (dst2) dst2[(size_t)r * C + c0 + tx] = v;
    }
    __syncthreads();
#pragma unroll
    for (int j = 0; j < 4; j++) {
        int c = c0 + ty + j * 8;
        dstT[(size_t)c * R + r0 + tx] = tile[tx][ty + j * 8];
    }
}

// ====== out GEMM: out[m][o] = msgs[m][:2048] @ Wout + bias (R7-verified) ======
// 64x128 tile, 512 threads = 8 waves. gld16 staging with pre-swizzled
// source chunks (XOR (l&7)^(l>>3), rule #21 both-sides), XOR-swizzled
// ds_read_b128, double-buffered K-loop with one barrier per K-step.
__global__ __launch_bounds__(512) void out_kernel(const short* __restrict__ msgs,
                                                  const short* __restrict__ WoutT,
                                                  const float* __restrict__ bias,
                                                  float* __restrict__ out) {
    __shared__ short sA[2][64 * 64];    // 8 KB x2: [64 m][8 chunks of 8 k]
    __shared__ short sB[2][128 * 64];   // 16 KB x2: [128 n][8 chunks of 8 k]
    int mt = blockIdx.x, nt = blockIdx.y;
    int tid = threadIdx.x, w = tid >> 6, l = tid & 63, lq = l & 15, quad = l >> 4;
    const short* Arow = msgs  + (size_t)(mt * 64)  * (H_ * F_);
    const short* Brow = WoutT + (size_t)(nt * 128) * (H_ * F_);
    int xk = (l & 7) ^ (l >> 3);   // pre-swizzled source chunk (row%8 == l>>3)

    f32x4 acc[4];
#pragma unroll
    for (int i = 0; i < 4; i++) acc[i] = (f32x4)(0.f);

#define STAGE_OUT(KB, BI) do {                                               \
        gld16(&Arow[(size_t)(w * 8 + (l >> 3)) * (H_ * F_) + (KB) * 64 + xk * 8], \
              &sA[BI][w * 8 * 64]);                                          \
        gld16(&Brow[(size_t)(w * 16 + (l >> 3)) * (H_ * F_) + (KB) * 64 + xk * 8], \
              &sB[BI][w * 16 * 64]);                                         \
        gld16(&Brow[(size_t)(w * 16 + 8 + (l >> 3)) * (H_ * F_) + (KB) * 64 + xk * 8], \
              &sB[BI][(w * 16 + 8) * 64]);                                   \
    } while (0)

    STAGE_OUT(0, 0);
    __syncthreads();

#pragma unroll 1
    for (int kb = 0; kb < 32; kb++) {
        int cur = kb & 1;
        if (kb < 31) STAGE_OUT(kb + 1, cur ^ 1);
        int arow = (w & 3) * 16 + lq;
#pragma unroll
        for (int kk = 0; kk < 2; kk++) {
            short8 af = *(const short8*)&sA[cur][arow * 64 + (((kk * 4 + quad) ^ (arow & 7)) * 8)];
#pragma unroll
            for (int ct = 0; ct < 4; ct++) {
                int brow = (w >> 2) * 64 + ct * 16 + lq;
                short8 bf = *(const short8*)&sB[cur][brow * 64 + (((kk * 4 + quad) ^ (brow & 7)) * 8)];
                acc[ct] = __builtin_amdgcn_mfma_f32_16x16x32_bf16(af, bf, acc[ct], 0, 0, 0);
            }
        }
        __syncthreads();
    }

#pragma unroll
    for (int ct = 0; ct < 4; ct++) {
        int gcol = nt * 128 + (w >> 2) * 64 + ct * 16 + lq;
        float bv = bias[gcol];
#pragma unroll
        for (int r = 0; r < 4; r++) {
            int row = mt * 64 + (w & 3) * 16 + quad * 4 + r;
            out[(size_t)row * O_ + gcol] = acc[ct][r] + bv;
        }
    }
}

// ============ fused flash attention, double-buffered pipeline ============
// Block: 512 threads = 8 waves, 128 q (wave w owns q = q0 + w*16 + lq).
// BN=64 keys/iter. VERIFIED geometry frozen: 512 blocks / grid (16,32) /
// 1 block/CU / 128 KB LDS. Session constraints (hardware-measured):
//  - Any geometry change collapses lockstep cache reuse (R2-R4:
//    FETCH 41.6 MB -> 270-910 MB).
//  - Counted-vmcnt 2-barrier loop slower than 1-barrier loop (R5).
//  - Accumulator ceiling: oacc[16] f32x4 + aq[8] is the max; more spills
//    (R4/R8: VGPR capped 128, WRITE_SIZE +37-68 MB, -70%).
//  - Pipe budget at 220 us: MFMA ~70, LDS-read ~94, VALU ~79 (overlap 1.1x).
// R10 change: phase-0 W-chunk double-buffer (kvTfB idle in phase 0) using
// the same verified stage-next/compute-cur/barrier shape as phase 1:
// 8 barriers -> 5, W staging overlapped with MFMA. Phase 1 byte-identical.

// stage key-tile KT: K rows into KVF [64][256] (XOR b^(r&31)),
// V^T rows into KVTF [256][64] (XOR b^(r&7)); 8 waves, 8 gld16/lane.
#define STAGE_KV(KT, KVF, KVTF) do {                                         \
    _Pragma("unroll")                                                        \
    for (int i_ = 0; i_ < 4; i_++) {                                         \
        int rk_ = w * 8 + i_ * 2 + (l >> 5);                                 \
        int bk_ = (l & 31) ^ (rk_ & 31);                                     \
        gld16(&Xb[(size_t)((KT) * 64 + rk_) * F_ + bk_ * 8],                 \
              &KVF[(w * 8 + i_ * 2) * 256]);                                 \
        int rt_ = w * 32 + i_ * 8 + (l >> 3);                                \
        int bt_ = (l & 7) ^ (rt_ & 7);                                       \
        gld16(&XTb[(size_t)rt_ * N_ + (KT) * 64 + bt_ * 8],                  \
              &KVTF[(w * 32 + i_ * 8) * 64]);                                \
    }                                                                        \
} while (0)

#define COMPUTE_KT(KVF, KVTF) do {                                           \
    f32x4 sacc[4];                                                           \
    _Pragma("unroll")                                                        \
    for (int ct = 0; ct < 4; ct++) sacc[ct] = (f32x4)(0.f);                  \
    __builtin_amdgcn_s_setprio(1);                                           \
    _Pragma("unroll")                                                        \
    for (int kk = 0; kk < 8; kk++) {                                         \
        _Pragma("unroll")                                                    \
        for (int ct = 0; ct < 4; ct++) {                                     \
            int arow = ct * 16 + lq;                                         \
            int ab = (kk * 4 + quad) ^ (arow & 31);                          \
            short8 af = *(const short8*)&KVF[arow * 256 + ab * 8];           \
            sacc[ct] = __builtin_amdgcn_mfma_f32_16x16x32_bf16(af, aq[kk], sacc[ct], 0, 0, 0); \
        }                                                                    \
    }                                                                        \
    __builtin_amdgcn_s_setprio(0);                                           \
    float mx = -INFINITY;                                                    \
    _Pragma("unroll")                                                        \
    for (int ct = 0; ct < 4; ct++)                                           \
        _Pragma("unroll")                                                    \
        for (int r_ = 0; r_ < 4; r_++) mx = fmaxf(mx, sacc[ct][r_]);         \
    mx = fmaxf(mx, __shfl_xor(mx, 16));                                      \
    mx = fmaxf(mx, __shfl_xor(mx, 32));                                      \
    if (!__all(mx - m_q <= 8.0f)) {      /* T13 defer-max, THR=8 */          \
        float mn = fmaxf(m_q, mx);                                           \
        float alpha = exp2f(m_q - mn);                                       \
        m_q = mn;                                                            \
        l_q *= alpha;                                                        \
        _Pragma("unroll")                                                    \
        for (int ct = 0; ct < 16; ct++)                                      \
            _Pragma("unroll")                                                \
            for (int r_ = 0; r_ < 4; r_++) oacc[ct][r_] *= alpha;            \
    }                                                                        \
    float pv[4][4]; float s_ = 0.f;                                          \
    _Pragma("unroll")                                                        \
    for (int ct = 0; ct < 4; ct++)                                           \
        _Pragma("unroll")                                                    \
        for (int r_ = 0; r_ < 4; r_++) {                                     \
            pv[ct][r_] = exp2f(sacc[ct][r_] - m_q);                          \
            s_ += pv[ct][r_];                                                \
        }                                                                    \
    s_ += __shfl_xor(s_, 16);                                                \
    s_ += __shfl_xor(s_, 32);                                                \
    l_q += s_;                                                               \
    unsigned int w2[4][2];                                                   \
    _Pragma("unroll")                                                        \
    for (int ct = 0; ct < 4; ct++) {                                         \
        w2[ct][0] = cvtpk(pv[ct][0], pv[ct][1]);                             \
        w2[ct][1] = cvtpk(pv[ct][2], pv[ct][3]);                             \
    }                                                                        \
    int sl0 = (2 * (quad & 1)) * 16 + lq;                                    \
    int sl1 = sl0 + 16;                                                      \
    bool hi = (quad >> 1) != 0;                                              \
    short8 pfrag[2];                                                         \
    _Pragma("unroll")                                                        \
    for (int kk = 0; kk < 2; kk++) {                                         \
        unsigned int u0 = __shfl((int)w2[2 * kk][0], sl0);                   \
        unsigned int u1 = __shfl((int)w2[2 * kk][1], sl0);                   \
        unsigned int u2 = __shfl((int)w2[2 * kk][0], sl1);                   \
        unsigned int u3 = __shfl((int)w2[2 * kk][1], sl1);                   \
        unsigned int v0 = __shfl((int)w2[2 * kk + 1][0], sl0);               \
        unsigned int v1 = __shfl((int)w2[2 * kk + 1][1], sl0);               \
        unsigned int v2 = __shfl((int)w2[2 * kk + 1][0], sl1);               \
        unsigned int v3 = __shfl((int)w2[2 * kk + 1][1], sl1);               \
        u32x4 pk = { hi ? v0 : u0, hi ? v1 : u1, hi ? v2 : u2, hi ? v3 : u3 }; \
        pfrag[kk] = __builtin_bit_cast(short8, pk);                          \
    }                                                                        \
    __builtin_amdgcn_s_setprio(1);                                           \
    _Pragma("unroll")                                                        \
    for (int ct = 0; ct < 16; ct++) {                                        \
        int arow = ct * 16 + lq;                                             \
        short8 a0 = *(const short8*)&KVTF[arow * 64 + ((quad) ^ (arow & 7)) * 8]; \
        short8 a1 = *(const short8*)&KVTF[arow * 64 + ((4 + quad) ^ (arow & 7)) * 8]; \
        oacc[ct] = __builtin_amdgcn_mfma_f32_16x16x32_bf16(a0, pfrag[0], oacc[ct], 0, 0, 0); \
        oacc[ct] = __builtin_amdgcn_mfma_f32_16x16x32_bf16(a1, pfrag[1], oacc[ct], 0, 0, 0); \
    }                                                                        \
    __builtin_amdgcn_s_setprio(0);                                           \
} while (0)

__global__ __launch_bounds__(512) void attn_kernel(const short* __restrict__ X,
                                                   const short* __restrict__ WhT,
                                                   const short* __restrict__ XT,
                                                   short* __restrict__ msgs) {
    __shared__ short kvfA[64 * 256];    // 32 KB
    __shared__ short kvfB[64 * 256];    // 32 KB
    __shared__ short kvTfA[256 * 64];   // 32 KB
    __shared__ short kvTfB[256 * 64];   // 32 KB

    int qt = blockIdx.x, bh = blockIdx.y, b = bh >> 3, h = bh & 7;
    int tid = threadIdx.x, w = tid >> 6, l = tid & 63, lq = l & 15, quad = l >> 4;
    int q0 = qt * 128;

    const short* Xb  = X  + (size_t)b * N_ * F_;
    const short* XTb = XT + (size_t)b * F_ * N_;
    const short* Whh = WhT + (size_t)h * F_ * F_;

    f32x4 oacc[16];
    short8 aq[8];

    // ---------- phase 0: Q = (X qtile @ Wh) * SCALE_QK (128 q rows) ----------
    // W chunks double-buffered kvTfA/kvTfB (same stage-next/compute-cur/
    // barrier shape as phase 1); X staged once into kvfA/B.
#pragma unroll
    for (int i = 0; i < 16; i++) oacc[i] = (f32x4)(0.f);
    {   // stage X rows q0..q0+127: waves 0-3 -> kvfA, waves 4-7 -> kvfB
        short* xdst = (w < 4) ? kvfA : kvfB;
        int wl = w & 3;
#pragma unroll
        for (int i = 0; i < 8; i++) {
            int r = wl * 16 + i * 2 + (l >> 5);
            int bb = (l & 31) ^ (r & 31);
            gld16(&Xb[(size_t)(q0 + ((w >> 2) * 64) + r) * F_ + bb * 8],
                  &xdst[(wl * 16 + i * 2) * 256]);
        }
    }
    {   // stage W chunk 0 -> kvTfA
#pragma unroll
        for (int i = 0; i < 4; i++) {
            int rt = w * 32 + i * 8 + (l >> 3);
            int bt = (l & 7) ^ (rt & 7);
            gld16(&Whh[(size_t)rt * F_ + bt * 8], &kvTfA[(w * 32 + i * 8) * 64]);
        }
    }
    const short* xsrc = (w < 4) ? kvfA : kvfB;
    __syncthreads();   // drain X + W0 DMA
#pragma unroll 1
    for (int kb = 0; kb < 4; kb++) {
        short* wnext = (kb & 1) ? kvTfA : kvTfB;
        const short* wsrc = (kb & 1) ? kvTfB : kvTfA;
        if (kb < 3) {   // prefetch W chunk kb+1 into the other buffer
#pragma unroll
            for (int i = 0; i < 4; i++) {
                int rt = w * 32 + i * 8 + (l >> 3);
                int bt = (l & 7) ^ (rt & 7);
                gld16(&Whh[(size_t)rt * F_ + (kb + 1) * 64 + bt * 8],
                      &wnext[(w * 32 + i * 8) * 64]);
            }
        }
#pragma unroll
        for (int kk = 0; kk < 2; kk++) {
            int arow = (w & 3) * 16 + lq;
            int ab = (kb * 8 + kk * 4 + quad) ^ (arow & 31);
            short8 af = *(const short8*)&xsrc[arow * 256 + ab * 8];
#pragma unroll
            for (int ct = 0; ct < 16; ct++) {
                int brow = ct * 16 + lq;
                int bb = (kk * 4 + quad) ^ (brow & 7);
                short8 bf = *(const short8*)&wsrc[brow * 64 + bb * 8];
                oacc[ct] = __builtin_amdgcn_mfma_f32_16x16x32_bf16(af, bf, oacc[ct], 0, 0, 0);
            }
        }
        __syncthreads();   // wsrc reads done + wnext prefetch drained
    }
    // (kb3 trailing barrier == all W reads done; reuse kvTfA/B as Q)
    {
        short* qdst = (w < 4) ? kvTfA : kvTfB;
#pragma unroll
        for (int ct = 0; ct < 16; ct++) {
#pragma unroll
            for (int r = 0; r < 4; r++) {
                int row = (w & 3) * 16 + quad * 4 + r;
                int col = ct * 16 + lq;
                int pb = (col >> 3) ^ (row & 31);
                qdst[row * 256 + pb * 8 + (col & 7)] = f2bf(oacc[ct][r] * SCALE_QK);
            }
        }
        __syncthreads();
#pragma unroll
        for (int kk = 0; kk < 8; kk++) {   // aq: B-frag Q[q=(w&3)*16+lq][kk*32+quad*8..]
            int row = (w & 3) * 16 + lq;
            int ab = (kk * 4 + quad) ^ (row & 31);
            aq[kk] = *(const short8*)&qdst[row * 256 + ab * 8];
        }
    }
    __syncthreads();   // all aq reads done before tile-0 DMA overwrites kvTfA

    // ---------- phase 1: pipelined flash attention (byte-identical) ----------
#pragma unroll
    for (int i = 0; i < 16; i++) oacc[i] = (f32x4)(0.f);
    float m_q = -INFINITY, l_q = 0.f;   // state for q = q0 + w*16 + lq

    STAGE_KV(0, kvfA, kvTfA);
    __syncthreads();   // drain tile-0 DMA

#pragma unroll 1
    for (int kt2 = 0; kt2 < 16; kt2++) {
        // half A: prefetch tile 2*kt2+1 -> B pair, compute from A pair
        STAGE_KV(2 * kt2 + 1, kvfB, kvTfB);
        COMPUTE_KT(kvfA, kvTfA);
        __syncthreads();   // all A-reads done + B-prefetch (issued pre-compute) drained
        // half B: prefetch tile (2*kt2+2)&31 -> A pair, compute from B pair
        STAGE_KV((2 * kt2 + 2) & 31, kvfA, kvTfA);   // last iter refetches tile 0 (unused, harmless)
        COMPUTE_KT(kvfB, kvTfB);
        __syncthreads();
    }

    // epilogue: per-lane q = q0 + w*16 + lq; feats ct*16 + quad*4 + r
    float inv = 1.f / l_q;
    short* Mout = msgs + (size_t)(b * N_ + q0 + w * 16 + lq) * (H_ * F_) + h * F_;
#pragma unroll
    for (int ct = 0; ct < 16; ct++) {
        s16x4 v4 = { f2bf(oacc[ct][0] * inv), f2bf(oacc[ct][1] * inv),
                     f2bf(oacc[ct][2] * inv), f2bf(oacc[ct][3] * inv) };
        *(s16x4*)&Mout[ct * 16 + quad * 4] = v4;
    }
}

extern "C" void kernel_launch(void* const* d_in, const int* in_sizes, int n_in,
                              void* d_out, int out_size, void* d_ws, size_t ws_size,
                              hipStream_t stream) {
    const float* nodes = (const float*)d_in[0];   // [4,2048,256] f32
    const float* Wh    = (const float*)d_in[1];   // [8,256,256]  f32
    const float* Wout  = (const float*)d_in[2];   // [2048,256]   f32
    const float* bias  = (const float*)d_in[3];   // [256]        f32
    float* out = (float*)d_out;                   // [4,2048,256] f32

    char* ws = (char*)d_ws;
    short* msgs   = (short*)(ws);                   // [8192][2048] bf16 = 32 MB
    short* WhT    = (short*)(ws + 33554432);        // [8][256][256]       1 MB
    short* WoutT  = (short*)(ws + 34603008);        // [256][2048]         1 MB
    short* XT     = (short*)(ws + 35651584);        // [4][256][2048]      4 MB
    short* Xbf    = (short*)(ws + 39845888);        // [4][2048][256]      4 MB

    hipLaunchKernelGGL(prep_kernel, dim3(3072), dim3(32, 8), 0, stream,
                       nodes, Wh, Wout, Xbf, XT, WhT, WoutT);
    hipLaunchKernelGGL(attn_kernel, dim3(16, 32), dim3(512), 0, stream, Xbf, WhT, XT, msgs);
    hipLaunchKernelGGL(out_kernel,  dim3(128, 2), dim3(512), 0, stream, msgs, WoutT, bias, out);
}

// Round 11
// 287.661 us; speedup vs baseline: 1.0253x; 1.0253x over previous
//
#include <hip/hip_runtime.h>
#include <hip/hip_bf16.h>

#define B_ 4
#define N_ 2048
#define F_ 256
#define H_ 8
#define O_ 256

// log2(e)/16 folded into Q so softmax can use exp2f (exact softmax, monotone map)
#define SCALE_QK 0.09016844005556021f

typedef __attribute__((ext_vector_type(8))) short short8;
typedef __attribute__((ext_vector_type(4))) short s16x4;
typedef __attribute__((ext_vector_type(4))) float f32x4;
typedef __attribute__((ext_vector_type(4))) unsigned int u32x4;

static __device__ __forceinline__ float bf2f(short u) {
    unsigned int x = ((unsigned int)(unsigned short)u) << 16;
    return __builtin_bit_cast(float, x);
}
static __device__ __forceinline__ short f2bf(float f) {
    unsigned int x = __builtin_bit_cast(unsigned int, f);
    unsigned int lsb = (x >> 16) & 1u;
    x += 0x7fffu + lsb;
    return (short)(x >> 16);
}
// packed f32x2 -> bf16x2 in one instruction (RNE); no builtin on gfx950
static __device__ __forceinline__ unsigned int cvtpk(float a, float b) {
    unsigned int r;
    asm("v_cvt_pk_bf16_f32 %0, %1, %2" : "=v"(r) : "v"(a), "v"(b));
    return r;
}

// async global->LDS 16B/lane; LDS dst is wave-uniform base + lane*16
static __device__ __forceinline__ void gld16(const short* g, short* l) {
    __builtin_amdgcn_global_load_lds(
        (const __attribute__((address_space(1))) void*)g,
        (__attribute__((address_space(3))) void*)l, 16, 0, 0);
}

// ---- f32 -> bf16 transpose (+ optional straight copy): dstT[c][r] = dst2[r][c] = bf16(src[r][c])
// NOTE (R10): merging the three launches of this kernel into one 3072-block
// dispatch was ~5 us SLOWER than three back-to-back launches — keep separate.
__global__ __launch_bounds__(256) void cvtT_kernel(const float* __restrict__ src,
                                                   short* __restrict__ dstT,
                                                   short* __restrict__ dst2,
                                                   int R, int C) {
    __shared__ short tile[32][33];
    src  += (size_t)blockIdx.z * R * C;
    dstT += (size_t)blockIdx.z * R * C;
    if (dst2) dst2 += (size_t)blockIdx.z * R * C;
    int tx = threadIdx.x, ty = threadIdx.y;           // 32 x 8
    int c0 = blockIdx.x * 32, r0 = blockIdx.y * 32;
#pragma unroll
    for (int j = 0; j < 4; j++) {
        int r = r0 + ty + j * 8;
        short v = f2bf(src[(size_t)r * C + c0 + tx]);
        tile[ty + j * 8][tx] = v;
        if (dst2) dst2[(size_t)r * C + c0 + tx] = v;
    }
    __syncthreads();
#pragma unroll
    for (int j = 0; j < 4; j++) {
        int c = c0 + ty + j * 8;
        dstT[(size_t)c * R + r0 + tx] = tile[tx][ty + j * 8];
    }
}

// ====== out GEMM: out[m][o] = msgs[m][:2048] @ Wout + bias (R7-verified) ======
// 64x128 tile, 512 threads = 8 waves. gld16 staging with pre-swizzled
// source chunks (XOR (l&7)^(l>>3), rule #21 both-sides), XOR-swizzled
// ds_read_b128, double-buffered K-loop with one barrier per K-step.
__global__ __launch_bounds__(512) void out_kernel(const short* __restrict__ msgs,
                                                  const short* __restrict__ WoutT,
                                                  const float* __restrict__ bias,
                                                  float* __restrict__ out) {
    __shared__ short sA[2][64 * 64];    // 8 KB x2: [64 m][8 chunks of 8 k]
    __shared__ short sB[2][128 * 64];   // 16 KB x2: [128 n][8 chunks of 8 k]
    int mt = blockIdx.x, nt = blockIdx.y;
    int tid = threadIdx.x, w = tid >> 6, l = tid & 63, lq = l & 15, quad = l >> 4;
    const short* Arow = msgs  + (size_t)(mt * 64)  * (H_ * F_);
    const short* Brow = WoutT + (size_t)(nt * 128) * (H_ * F_);
    int xk = (l & 7) ^ (l >> 3);   // pre-swizzled source chunk (row%8 == l>>3)

    f32x4 acc[4];
#pragma unroll
    for (int i = 0; i < 4; i++) acc[i] = (f32x4)(0.f);

#define STAGE_OUT(KB, BI) do {                                               \
        gld16(&Arow[(size_t)(w * 8 + (l >> 3)) * (H_ * F_) + (KB) * 64 + xk * 8], \
              &sA[BI][w * 8 * 64]);                                          \
        gld16(&Brow[(size_t)(w * 16 + (l >> 3)) * (H_ * F_) + (KB) * 64 + xk * 8], \
              &sB[BI][w * 16 * 64]);                                         \
        gld16(&Brow[(size_t)(w * 16 + 8 + (l >> 3)) * (H_ * F_) + (KB) * 64 + xk * 8], \
              &sB[BI][(w * 16 + 8) * 64]);                                   \
    } while (0)

    STAGE_OUT(0, 0);
    __syncthreads();

#pragma unroll 1
    for (int kb = 0; kb < 32; kb++) {
        int cur = kb & 1;
        if (kb < 31) STAGE_OUT(kb + 1, cur ^ 1);
        int arow = (w & 3) * 16 + lq;
#pragma unroll
        for (int kk = 0; kk < 2; kk++) {
            short8 af = *(const short8*)&sA[cur][arow * 64 + (((kk * 4 + quad) ^ (arow & 7)) * 8)];
#pragma unroll
            for (int ct = 0; ct < 4; ct++) {
                int brow = (w >> 2) * 64 + ct * 16 + lq;
                short8 bf = *(const short8*)&sB[cur][brow * 64 + (((kk * 4 + quad) ^ (brow & 7)) * 8)];
                acc[ct] = __builtin_amdgcn_mfma_f32_16x16x32_bf16(af, bf, acc[ct], 0, 0, 0);
            }
        }
        __syncthreads();
    }

#pragma unroll
    for (int ct = 0; ct < 4; ct++) {
        int gcol = nt * 128 + (w >> 2) * 64 + ct * 16 + lq;
        float bv = bias[gcol];
#pragma unroll
        for (int r = 0; r < 4; r++) {
            int row = mt * 64 + (w & 3) * 16 + quad * 4 + r;
            out[(size_t)row * O_ + gcol] = acc[ct][r] + bv;
        }
    }
}

// ============ fused flash attention, double-buffered pipeline ============
// Block: 512 threads = 8 waves, 128 q (wave w owns q = q0 + w*16 + lq).
// BN=64 keys/iter. VERIFIED STATE (289.0 us total, attn 220 us): geometry
// frozen at 512 blocks / grid (16,32) / 1 block/CU / 128 KB LDS.
// Session constraints (all hardware-measured, rounds R2-R10):
//  - Any geometry change (2 blocks/CU, XCD swizzle, 2-head/256-block)
//    collapses lockstep cache reuse: FETCH 41.6 MB -> 270-910 MB.
//  - Counted-vmcnt 2-barrier loop slower than this 1-barrier loop (R5):
//    prefetch is issued pre-compute, so the barrier drain is already-landed.
//  - Register ceiling: oacc[16] f32x4 + aq[8] is the max; key-split (R8)
//    and 2-head (R4) variants spill (VGPR capped 128, WRITE_SIZE +37-68 MB).
//  - Phase-0 W double-buffer: no effect (R10) — already overlapped.
//  - VALU trim verified (R6): T13 defer-max + v_cvt_pk, 227 -> 220 us.
//  - Pipe budget at 220 us: MFMA ~70 us (floor), LDS-read ~94, VALU ~79 —
//    near-additive per-wave serial chain at 2 waves/SIMD. Escape would need
//    32x32-MFMA formulation within the 64-acc-reg budget (unverified
//    fragment layouts; R1 showed blind layout derivation fails).

// stage key-tile KT: K rows into KVF [64][256] (XOR b^(r&31)),
// V^T rows into KVTF [256][64] (XOR b^(r&7)); 8 waves, 8 gld16/lane.
#define STAGE_KV(KT, KVF, KVTF) do {                                         \
    _Pragma("unroll")                                                        \
    for (int i_ = 0; i_ < 4; i_++) {                                         \
        int rk_ = w * 8 + i_ * 2 + (l >> 5);                                 \
        int bk_ = (l & 31) ^ (rk_ & 31);                                     \
        gld16(&Xb[(size_t)((KT) * 64 + rk_) * F_ + bk_ * 8],                 \
              &KVF[(w * 8 + i_ * 2) * 256]);                                 \
        int rt_ = w * 32 + i_ * 8 + (l >> 3);                                \
        int bt_ = (l & 7) ^ (rt_ & 7);                                       \
        gld16(&XTb[(size_t)rt_ * N_ + (KT) * 64 + bt_ * 8],                  \
              &KVTF[(w * 32 + i_ * 8) * 64]);                                \
    }                                                                        \
} while (0)

#define COMPUTE_KT(KVF, KVTF) do {                                           \
    f32x4 sacc[4];                                                           \
    _Pragma("unroll")                                                        \
    for (int ct = 0; ct < 4; ct++) sacc[ct] = (f32x4)(0.f);                  \
    __builtin_amdgcn_s_setprio(1);                                           \
    _Pragma("unroll")                                                        \
    for (int kk = 0; kk < 8; kk++) {                                         \
        _Pragma("unroll")                                                    \
        for (int ct = 0; ct < 4; ct++) {                                     \
            int arow = ct * 16 + lq;                                         \
            int ab = (kk * 4 + quad) ^ (arow & 31);                          \
            short8 af = *(const short8*)&KVF[arow * 256 + ab * 8];           \
            sacc[ct] = __builtin_amdgcn_mfma_f32_16x16x32_bf16(af, aq[kk], sacc[ct], 0, 0, 0); \
        }                                                                    \
    }                                                                        \
    __builtin_amdgcn_s_setprio(0);                                           \
    float mx = -INFINITY;                                                    \
    _Pragma("unroll")                                                        \
    for (int ct = 0; ct < 4; ct++)                                           \
        _Pragma("unroll")                                                    \
        for (int r_ = 0; r_ < 4; r_++) mx = fmaxf(mx, sacc[ct][r_]);         \
    mx = fmaxf(mx, __shfl_xor(mx, 16));                                      \
    mx = fmaxf(mx, __shfl_xor(mx, 32));                                      \
    if (!__all(mx - m_q <= 8.0f)) {      /* T13 defer-max, THR=8 */          \
        float mn = fmaxf(m_q, mx);                                           \
        float alpha = exp2f(m_q - mn);                                       \
        m_q = mn;                                                            \
        l_q *= alpha;                                                        \
        _Pragma("unroll")                                                    \
        for (int ct = 0; ct < 16; ct++)                                      \
            _Pragma("unroll")                                                \
            for (int r_ = 0; r_ < 4; r_++) oacc[ct][r_] *= alpha;            \
    }                                                                        \
    float pv[4][4]; float s_ = 0.f;                                          \
    _Pragma("unroll")                                                        \
    for (int ct = 0; ct < 4; ct++)                                           \
        _Pragma("unroll")                                                    \
        for (int r_ = 0; r_ < 4; r_++) {                                     \
            pv[ct][r_] = exp2f(sacc[ct][r_] - m_q);                          \
            s_ += pv[ct][r_];                                                \
        }                                                                    \
    s_ += __shfl_xor(s_, 16);                                                \
    s_ += __shfl_xor(s_, 32);                                                \
    l_q += s_;                                                               \
    unsigned int w2[4][2];                                                   \
    _Pragma("unroll")                                                        \
    for (int ct = 0; ct < 4; ct++) {                                         \
        w2[ct][0] = cvtpk(pv[ct][0], pv[ct][1]);                             \
        w2[ct][1] = cvtpk(pv[ct][2], pv[ct][3]);                             \
    }                                                                        \
    int sl0 = (2 * (quad & 1)) * 16 + lq;                                    \
    int sl1 = sl0 + 16;                                                      \
    bool hi = (quad >> 1) != 0;                                              \
    short8 pfrag[2];                                                         \
    _Pragma("unroll")                                                        \
    for (int kk = 0; kk < 2; kk++) {                                         \
        unsigned int u0 = __shfl((int)w2[2 * kk][0], sl0);                   \
        unsigned int u1 = __shfl((int)w2[2 * kk][1], sl0);                   \
        unsigned int u2 = __shfl((int)w2[2 * kk][0], sl1);                   \
        unsigned int u3 = __shfl((int)w2[2 * kk][1], sl1);                   \
        unsigned int v0 = __shfl((int)w2[2 * kk + 1][0], sl0);               \
        unsigned int v1 = __shfl((int)w2[2 * kk + 1][1], sl0);               \
        unsigned int v2 = __shfl((int)w2[2 * kk + 1][0], sl1);               \
        unsigned int v3 = __shfl((int)w2[2 * kk + 1][1], sl1);               \
        u32x4 pk = { hi ? v0 : u0, hi ? v1 : u1, hi ? v2 : u2, hi ? v3 : u3 }; \
        pfrag[kk] = __builtin_bit_cast(short8, pk);                          \
    }                                                                        \
    __builtin_amdgcn_s_setprio(1);                                           \
    _Pragma("unroll")                                                        \
    for (int ct = 0; ct < 16; ct++) {                                        \
        int arow = ct * 16 + lq;                                             \
        short8 a0 = *(const short8*)&KVTF[arow * 64 + ((quad) ^ (arow & 7)) * 8]; \
        short8 a1 = *(const short8*)&KVTF[arow * 64 + ((4 + quad) ^ (arow & 7)) * 8]; \
        oacc[ct] = __builtin_amdgcn_mfma_f32_16x16x32_bf16(a0, pfrag[0], oacc[ct], 0, 0, 0); \
        oacc[ct] = __builtin_amdgcn_mfma_f32_16x16x32_bf16(a1, pfrag[1], oacc[ct], 0, 0, 0); \
    }                                                                        \
    __builtin_amdgcn_s_setprio(0);                                           \
} while (0)

__global__ __launch_bounds__(512) void attn_kernel(const short* __restrict__ X,
                                                   const short* __restrict__ WhT,
                                                   const short* __restrict__ XT,
                                                   short* __restrict__ msgs) {
    __shared__ short kvfA[64 * 256];    // 32 KB
    __shared__ short kvfB[64 * 256];    // 32 KB
    __shared__ short kvTfA[256 * 64];   // 32 KB
    __shared__ short kvTfB[256 * 64];   // 32 KB

    int qt = blockIdx.x, bh = blockIdx.y, b = bh >> 3, h = bh & 7;
    int tid = threadIdx.x, w = tid >> 6, l = tid & 63, lq = l & 15, quad = l >> 4;
    int q0 = qt * 128;

    const short* Xb  = X  + (size_t)b * N_ * F_;
    const short* XTb = XT + (size_t)b * F_ * N_;
    const short* Whh = WhT + (size_t)h * F_ * F_;

    f32x4 oacc[16];
    short8 aq[8];

    // ---------- phase 0: Q = (X qtile @ Wh) * SCALE_QK (128 q rows) ----------
#pragma unroll
    for (int i = 0; i < 16; i++) oacc[i] = (f32x4)(0.f);
    {   // stage X rows q0..q0+127: waves 0-3 -> kvfA, waves 4-7 -> kvfB
        short* xdst = (w < 4) ? kvfA : kvfB;
        int wl = w & 3;
#pragma unroll
        for (int i = 0; i < 8; i++) {
            int r = wl * 16 + i * 2 + (l >> 5);
            int bb = (l & 31) ^ (r & 31);
            gld16(&Xb[(size_t)(q0 + ((w >> 2) * 64) + r) * F_ + bb * 8],
                  &xdst[(wl * 16 + i * 2) * 256]);
        }
    }
    const short* xsrc = (w < 4) ? kvfA : kvfB;
#pragma unroll 1
    for (int kb = 0; kb < 4; kb++) {
        __syncthreads();   // prev kb's W reads done
#pragma unroll
        for (int i = 0; i < 4; i++) {   // stage WhT[h][0:256][kb*64..+63] -> kvTfA
            int rt = w * 32 + i * 8 + (l >> 3);
            int bt = (l & 7) ^ (rt & 7);
            gld16(&Whh[(size_t)rt * F_ + kb * 64 + bt * 8], &kvTfA[(w * 32 + i * 8) * 64]);
        }
        __syncthreads();   // drains DMA (X on kb==0, W always)
#pragma unroll
        for (int kk = 0; kk < 2; kk++) {
            int arow = (w & 3) * 16 + lq;
            int ab = (kb * 8 + kk * 4 + quad) ^ (arow & 31);
            short8 af = *(const short8*)&xsrc[arow * 256 + ab * 8];
#pragma unroll
            for (int ct = 0; ct < 16; ct++) {
                int brow = ct * 16 + lq;
                int bb = (kk * 4 + quad) ^ (brow & 7);
                short8 bf = *(const short8*)&kvTfA[brow * 64 + bb * 8];
                oacc[ct] = __builtin_amdgcn_mfma_f32_16x16x32_bf16(af, bf, oacc[ct], 0, 0, 0);
            }
        }
    }
    __syncthreads();   // all W reads done; reuse kvTfA/B as Q [64 q][256 f], XOR b^(r&31)
    {
        short* qdst = (w < 4) ? kvTfA : kvTfB;
#pragma unroll
        for (int ct = 0; ct < 16; ct++) {
#pragma unroll
            for (int r = 0; r < 4; r++) {
                int row = (w & 3) * 16 + quad * 4 + r;
                int col = ct * 16 + lq;
                int pb = (col >> 3) ^ (row & 31);
                qdst[row * 256 + pb * 8 + (col & 7)] = f2bf(oacc[ct][r] * SCALE_QK);
            }
        }
        __syncthreads();
#pragma unroll
        for (int kk = 0; kk < 8; kk++) {   // aq: B-frag Q[q=(w&3)*16+lq][kk*32+quad*8..]
            int row = (w & 3) * 16 + lq;
            int ab = (kk * 4 + quad) ^ (row & 31);
            aq[kk] = *(const short8*)&qdst[row * 256 + ab * 8];
        }
    }
    __syncthreads();   // all aq reads done before tile-0 DMA overwrites kvTfA

    // ---------- phase 1: pipelined flash attention ----------
#pragma unroll
    for (int i = 0; i < 16; i++) oacc[i] = (f32x4)(0.f);
    float m_q = -INFINITY, l_q = 0.f;   // state for q = q0 + w*16 + lq

    STAGE_KV(0, kvfA, kvTfA);
    __syncthreads();   // drain tile-0 DMA

#pragma unroll 1
    for (int kt2 = 0; kt2 < 16; kt2++) {
        // half A: prefetch tile 2*kt2+1 -> B pair, compute from A pair
        STAGE_KV(2 * kt2 + 1, kvfB, kvTfB);
        COMPUTE_KT(kvfA, kvTfA);
        __syncthreads();   // all A-reads done + B-prefetch (issued pre-compute) drained
        // half B: prefetch tile (2*kt2+2)&31 -> A pair, compute from B pair
        STAGE_KV((2 * kt2 + 2) & 31, kvfA, kvTfA);   // last iter refetches tile 0 (unused, harmless)
        COMPUTE_KT(kvfB, kvTfB);
        __syncthreads();
    }

    // epilogue: per-lane q = q0 + w*16 + lq; feats ct*16 + quad*4 + r
    float inv = 1.f / l_q;
    short* Mout = msgs + (size_t)(b * N_ + q0 + w * 16 + lq) * (H_ * F_) + h * F_;
#pragma unroll
    for (int ct = 0; ct < 16; ct++) {
        s16x4 v4 = { f2bf(oacc[ct][0] * inv), f2bf(oacc[ct][1] * inv),
                     f2bf(oacc[ct][2] * inv), f2bf(oacc[ct][3] * inv) };
        *(s16x4*)&Mout[ct * 16 + quad * 4] = v4;
    }
}

extern "C" void kernel_launch(void* const* d_in, const int* in_sizes, int n_in,
                              void* d_out, int out_size, void* d_ws, size_t ws_size,
                              hipStream_t stream) {
    const float* nodes = (const float*)d_in[0];   // [4,2048,256] f32
    const float* Wh    = (const float*)d_in[1];   // [8,256,256]  f32
    const float* Wout  = (const float*)d_in[2];   // [2048,256]   f32
    const float* bias  = (const float*)d_in[3];   // [256]        f32
    float* out = (float*)d_out;                   // [4,2048,256] f32

    char* ws = (char*)d_ws;
    short* msgs   = (short*)(ws);                   // [8192][2048] bf16 = 32 MB
    short* WhT    = (short*)(ws + 33554432);        // [8][256][256]       1 MB
    short* WoutT  = (short*)(ws + 34603008);        // [256][2048]         1 MB
    short* XT     = (short*)(ws + 35651584);        // [4][256][2048]      4 MB
    short* Xbf    = (short*)(ws + 39845888);        // [4][2048][256]      4 MB

    dim3 tblk(32, 8, 1);
    hipLaunchKernelGGL(cvtT_kernel, dim3(8, 8, 8),  tblk, 0, stream, Wh,    WhT,   (short*)nullptr, 256,  256);
    hipLaunchKernelGGL(cvtT_kernel, dim3(8, 64, 1), tblk, 0, stream, Wout,  WoutT, (short*)nullptr, 2048, 256);
    hipLaunchKernelGGL(cvtT_kernel, dim3(8, 64, 4), tblk, 0, stream, nodes, XT,    Xbf,             2048, 256);

    hipLaunchKernelGGL(attn_kernel, dim3(16, 32), dim3(512), 0, stream, Xbf, WhT, XT, msgs);
    hipLaunchKernelGGL(out_kernel,  dim3(128, 2), dim3(512), 0, stream, msgs, WoutT, bias, out);
}